// Round 2
// baseline (241.407 us; speedup 1.0000x reference)
//
#include <hip/hip_runtime.h>
#include <math.h>

#define BDIM 512
#define IDIM 256
#define ODIM 512

// jnp.minimum(q, 1.0): NaN-propagating min with 1.0
__device__ __forceinline__ float np_min1(float q) {
    return (q < 1.0f) ? q : ((q != q) ? q : 1.0f);
}

// np.argmin update rule: strict < (first occurrence wins), NaN treated as
// minimal (first NaN wins).
__device__ __forceinline__ bool np_argmin_better(float s, float best) {
    return (s < best) || (isnan(s) && !isnan(best));
}

// rel_x[i,o] = 1 - S/D,
//   S = sum_b min(((1-t[b,o]) - (1-x[b,i])) / (1 - (1-x[b,i])), 1)   [seq over b]
//   D = sum_b (1 - x[b,i])                                           [seq over b]
// All ops fp32, numpy op-order, no contraction. Block = o, thread = i.
__global__ __launch_bounds__(256) void relx_kernel(const float* __restrict__ x,
                                                   const float* __restrict__ t,
                                                   float* __restrict__ relx) {
    int i = threadIdx.x;   // 0..255
    int o = blockIdx.x;    // 0..511
    float S = 0.0f, D = 0.0f;
    for (int b = 0; b < BDIM; ++b) {
        float xv = x[b * IDIM + i];          // coalesced
        float tv = t[b * ODIM + o];          // uniform -> scalar load
        float xc  = __fsub_rn(1.0f, xv);     // x_comp
        float tc  = __fsub_rn(1.0f, tv);     // t_comp
        float num = __fsub_rn(tc, xc);
        float den = __fsub_rn(1.0f, xc);     // NOT simply xv (rounding!)
        float q   = __fdiv_rn(num, den);
        S = __fadd_rn(S, np_min1(q));
        D = __fadd_rn(D, xc);
    }
    relx[i * ODIM + o] = __fsub_rn(1.0f, __fdiv_rn(S, D));
}

// rel_w[b,o] = 1 - S/D,
//   S = sum_i min(((1-t[b,o]) - (1-w[i,o])) / (1 - (1-w[i,o])), 1)   [seq over i]
//   D = sum_i (1 - w[i,o])                                           [seq over i]
// Block = b, thread = o.
__global__ __launch_bounds__(512) void relw_kernel(const float* __restrict__ w,
                                                   const float* __restrict__ t,
                                                   float* __restrict__ relw) {
    int o = threadIdx.x;   // 0..511
    int b = blockIdx.x;    // 0..511
    float tc = __fsub_rn(1.0f, t[b * ODIM + o]);
    float S = 0.0f, D = 0.0f;
    for (int i = 0; i < IDIM; ++i) {
        float wv  = w[i * ODIM + o];         // coalesced
        float wc  = __fsub_rn(1.0f, wv);     // w_comp
        float num = __fsub_rn(tc, wc);
        float den = __fsub_rn(1.0f, wc);
        float q   = __fdiv_rn(num, den);
        S = __fadd_rn(S, np_min1(q));
        D = __fadd_rn(D, wc);
    }
    relw[b * ODIM + o] = __fsub_rn(1.0f, __fdiv_rn(S, D));
}

// Both argmins + gathers, fp32 numpy-exact scores. Block = b, thread = o.
__global__ __launch_bounds__(512) void out_kernel(const float* __restrict__ x,
                                                  const float* __restrict__ w,
                                                  const float* __restrict__ relx,
                                                  const float* __restrict__ relw,
                                                  float* __restrict__ out) {
    __shared__ float xrow[IDIM];
    int o = threadIdx.x;   // 0..511
    int b = blockIdx.x;    // 0..511
    if (o < IDIM) xrow[o] = x[b * IDIM + o];
    __syncthreads();

    // ind_w: score = fl(fl(w + relw) - fl(w*relw))
    float rw = relw[b * ODIM + o];
    float best; int idx;
    {
        float w0 = w[o];                     // i = 0
        best = __fsub_rn(__fadd_rn(w0, rw), __fmul_rn(w0, rw));
        idx = 0;
        for (int i = 1; i < IDIM; ++i) {
            float wv = w[i * ODIM + o];      // coalesced
            float s  = __fsub_rn(__fadd_rn(wv, rw), __fmul_rn(wv, rw));
            if (np_argmin_better(s, best)) { best = s; idx = i; }
        }
    }
    float cw = fmaxf(xrow[idx], w[idx * ODIM + o]);
    out[BDIM * ODIM + b * ODIM + o] = cw;    // chosen_w = output 1

    // ind_x: score = fl(fl(x + relx) - fl(x*relx))
    {
        float x0 = xrow[0];
        float r0 = relx[o];
        best = __fsub_rn(__fadd_rn(x0, r0), __fmul_rn(x0, r0));
        idx = 0;
        for (int i = 1; i < IDIM; ++i) {
            float xv = xrow[i];              // LDS broadcast
            float rl = relx[i * ODIM + o];   // coalesced
            float s  = __fsub_rn(__fadd_rn(xv, rl), __fmul_rn(xv, rl));
            if (np_argmin_better(s, best)) { best = s; idx = i; }
        }
    }
    float cx = fmaxf(xrow[idx], w[idx * ODIM + o]);
    out[b * ODIM + o] = cx;                  // chosen_x = output 0
}

extern "C" void kernel_launch(void* const* d_in, const int* in_sizes, int n_in,
                              void* d_out, int out_size, void* d_ws, size_t ws_size,
                              hipStream_t stream) {
    const float* x = (const float*)d_in[0];  // (B, I)
    const float* w = (const float*)d_in[1];  // (I, O)
    const float* t = (const float*)d_in[2];  // (B, O)
    float* out = (float*)d_out;              // [chosen_x | chosen_w]

    char* ws = (char*)d_ws;
    float* relx = (float*)(ws);                      // I*O*4 = 512 KB
    float* relw = (float*)(ws + (IDIM * ODIM * 4));  // B*O*4 = 1 MB

    hipLaunchKernelGGL(relx_kernel, dim3(ODIM), dim3(IDIM), 0, stream, x, t, relx);
    hipLaunchKernelGGL(relw_kernel, dim3(BDIM), dim3(ODIM), 0, stream, w, t, relw);
    hipLaunchKernelGGL(out_kernel,  dim3(BDIM), dim3(ODIM), 0, stream, x, w, relx, relw, out);
}

// Round 3
// 184.035 us; speedup vs baseline: 1.3117x; 1.3117x over previous
//
#include <hip/hip_runtime.h>
#include <math.h>

#define BDIM 512
#define IDIM 256
#define ODIM 512

// jnp.minimum(q, 1.0): NaN-propagating min with 1.0
__device__ __forceinline__ float np_min1(float q) {
    return (q < 1.0f) ? q : ((q != q) ? q : 1.0f);
}

// np.argmin update rule: strict < (first occurrence wins), NaN-first.
__device__ __forceinline__ bool np_argmin_better(float s, float best) {
    return (s < best) || (isnan(s) && !isnan(best));
}

// rel_x[i,o] = 1 - S/D, sequential-in-b accumulation (numpy order),
// divides hoisted 8-wide for ILP. Block = o (512), thread = i (256).
__global__ __launch_bounds__(256) void relx_kernel(const float* __restrict__ x,
                                                   const float* __restrict__ t,
                                                   float* __restrict__ relx) {
    int i = threadIdx.x;   // 0..255
    int o = blockIdx.x;    // 0..511
    float S = 0.0f, D = 0.0f;
    for (int b = 0; b < BDIM; b += 8) {
        float q[8], xc[8];
        #pragma unroll
        for (int u = 0; u < 8; ++u) {
            float xv  = x[(b + u) * IDIM + i];   // coalesced
            float tv  = t[(b + u) * ODIM + o];   // uniform -> scalar load
            float xcv = __fsub_rn(1.0f, xv);     // x_comp
            float tc  = __fsub_rn(1.0f, tv);     // t_comp
            float num = __fsub_rn(tc, xcv);
            float den = __fsub_rn(1.0f, xcv);    // NOT simply xv (rounding!)
            q[u]  = np_min1(__fdiv_rn(num, den)); // independent chains
            xc[u] = xcv;
        }
        #pragma unroll
        for (int u = 0; u < 8; ++u) {            // exact sequential order
            S = __fadd_rn(S, q[u]);
            D = __fadd_rn(D, xc[u]);
        }
    }
    relx[i * ODIM + o] = __fsub_rn(1.0f, __fdiv_rn(S, D));
}

// Fused: rel_w[b,o] (sequential-in-i, 8-wide hoisted divides) + both argmins
// + gathers. Block = b (512), thread = o (512).
__global__ __launch_bounds__(512) void relw_out_kernel(const float* __restrict__ x,
                                                       const float* __restrict__ w,
                                                       const float* __restrict__ t,
                                                       const float* __restrict__ relx,
                                                       float* __restrict__ out) {
    __shared__ float xrow[IDIM];
    int o = threadIdx.x;   // 0..511
    int b = blockIdx.x;    // 0..511
    if (o < IDIM) xrow[o] = x[b * IDIM + o];

    // ---- phase 1: rel_w[b,o] ----
    float tc = __fsub_rn(1.0f, t[b * ODIM + o]);
    float S = 0.0f, D = 0.0f;
    for (int i = 0; i < IDIM; i += 8) {
        float q[8], wc[8];
        #pragma unroll
        for (int u = 0; u < 8; ++u) {
            float wv  = w[(i + u) * ODIM + o];   // coalesced
            float wcv = __fsub_rn(1.0f, wv);     // w_comp
            float num = __fsub_rn(tc, wcv);
            float den = __fsub_rn(1.0f, wcv);
            q[u]  = np_min1(__fdiv_rn(num, den));
            wc[u] = wcv;
        }
        #pragma unroll
        for (int u = 0; u < 8; ++u) {            // exact sequential order
            S = __fadd_rn(S, q[u]);
            D = __fadd_rn(D, wc[u]);
        }
    }
    float rw = __fsub_rn(1.0f, __fdiv_rn(S, D));
    __syncthreads();                             // xrow ready

    // ---- phase 2: ind_w, score = fl(fl(w+rw) - fl(w*rw)) ----
    float best; int idx;
    {
        float w0 = w[o];
        best = __fsub_rn(__fadd_rn(w0, rw), __fmul_rn(w0, rw));
        idx = 0;
        for (int i = 4; i <= IDIM - 4; i += 4) { // i=1..3 handled below
            ;
        }
        // simple unroll-4 with exact sequential update, starting at i=1
        int i = 1;
        for (; i + 4 <= IDIM; i += 4) {
            float s0, s1, s2, s3;
            {
                float a = w[(i+0) * ODIM + o]; s0 = __fsub_rn(__fadd_rn(a, rw), __fmul_rn(a, rw));
                float c = w[(i+1) * ODIM + o]; s1 = __fsub_rn(__fadd_rn(c, rw), __fmul_rn(c, rw));
                float d = w[(i+2) * ODIM + o]; s2 = __fsub_rn(__fadd_rn(d, rw), __fmul_rn(d, rw));
                float e = w[(i+3) * ODIM + o]; s3 = __fsub_rn(__fadd_rn(e, rw), __fmul_rn(e, rw));
            }
            if (np_argmin_better(s0, best)) { best = s0; idx = i + 0; }
            if (np_argmin_better(s1, best)) { best = s1; idx = i + 1; }
            if (np_argmin_better(s2, best)) { best = s2; idx = i + 2; }
            if (np_argmin_better(s3, best)) { best = s3; idx = i + 3; }
        }
        for (; i < IDIM; ++i) {
            float a = w[i * ODIM + o];
            float s = __fsub_rn(__fadd_rn(a, rw), __fmul_rn(a, rw));
            if (np_argmin_better(s, best)) { best = s; idx = i; }
        }
    }
    float cw = fmaxf(xrow[idx], w[idx * ODIM + o]);
    out[BDIM * ODIM + b * ODIM + o] = cw;        // chosen_w = output 1

    // ---- phase 3: ind_x, score = fl(fl(x+rel) - fl(x*rel)) ----
    {
        float x0 = xrow[0];
        float r0 = relx[o];
        best = __fsub_rn(__fadd_rn(x0, r0), __fmul_rn(x0, r0));
        idx = 0;
        int i = 1;
        for (; i + 4 <= IDIM; i += 4) {
            float s0, s1, s2, s3;
            {
                float a0 = xrow[i+0], r0_ = relx[(i+0) * ODIM + o];
                float a1 = xrow[i+1], r1_ = relx[(i+1) * ODIM + o];
                float a2 = xrow[i+2], r2_ = relx[(i+2) * ODIM + o];
                float a3 = xrow[i+3], r3_ = relx[(i+3) * ODIM + o];
                s0 = __fsub_rn(__fadd_rn(a0, r0_), __fmul_rn(a0, r0_));
                s1 = __fsub_rn(__fadd_rn(a1, r1_), __fmul_rn(a1, r1_));
                s2 = __fsub_rn(__fadd_rn(a2, r2_), __fmul_rn(a2, r2_));
                s3 = __fsub_rn(__fadd_rn(a3, r3_), __fmul_rn(a3, r3_));
            }
            if (np_argmin_better(s0, best)) { best = s0; idx = i + 0; }
            if (np_argmin_better(s1, best)) { best = s1; idx = i + 1; }
            if (np_argmin_better(s2, best)) { best = s2; idx = i + 2; }
            if (np_argmin_better(s3, best)) { best = s3; idx = i + 3; }
        }
        for (; i < IDIM; ++i) {
            float a = xrow[i];
            float r = relx[i * ODIM + o];
            float s = __fsub_rn(__fadd_rn(a, r), __fmul_rn(a, r));
            if (np_argmin_better(s, best)) { best = s; idx = i; }
        }
    }
    float cx = fmaxf(xrow[idx], w[idx * ODIM + o]);
    out[b * ODIM + o] = cx;                      // chosen_x = output 0
}

extern "C" void kernel_launch(void* const* d_in, const int* in_sizes, int n_in,
                              void* d_out, int out_size, void* d_ws, size_t ws_size,
                              hipStream_t stream) {
    const float* x = (const float*)d_in[0];  // (B, I)
    const float* w = (const float*)d_in[1];  // (I, O)
    const float* t = (const float*)d_in[2];  // (B, O)
    float* out = (float*)d_out;              // [chosen_x | chosen_w]

    float* relx = (float*)d_ws;              // I*O*4 = 512 KB

    hipLaunchKernelGGL(relx_kernel,    dim3(ODIM), dim3(IDIM), 0, stream, x, t, relx);
    hipLaunchKernelGGL(relw_out_kernel, dim3(BDIM), dim3(ODIM), 0, stream, x, w, t, relx, out);
}